// Round 1
// baseline (1120.000 us; speedup 1.0000x reference)
//
#include <hip/hip_runtime.h>

// Problem constants (from reference)
#define N_RAYS   16384
#define N_SAMP   256
#define GRID_N   160
#define GRID_VOX (GRID_N * GRID_N * GRID_N)   // 4,096,000

// XYZ_MIN = -1.2, XYZ_MAX = 1.2 ; u = (p - XYZ_MIN)/(MAX-MIN) * (160-1)
__device__ __constant__ float kXyzMin   = -1.2f;
__device__ __constant__ float kScale    = 159.0f / 2.4f;          // 66.25
// ACT_SHIFT = log(1/(1-1e-4) - 1) computed in double precision
__device__ __constant__ float kActShift = -9.21024036697530f;
__device__ __constant__ float kInterval = 0.01f;

__device__ __forceinline__ float sigmoidf_(float x) {
    return 1.0f / (1.0f + expf(-x));
}

__global__ __launch_bounds__(256)
void render_kernel(const float* __restrict__ ray_pts,   // [N_RAYS, N_SAMP, 3]
                   const float* __restrict__ dgrid,     // [1,160,160,160]
                   const float* __restrict__ kgrid,     // [3,160,160,160]
                   float* __restrict__ out_rgb,         // [N_RAYS, 3]
                   float* __restrict__ out_w,           // [N_RAYS, N_SAMP]
                   float* __restrict__ out_ainv)        // [N_RAYS]
{
    const int r    = blockIdx.x;
    const int s    = threadIdx.x;
    const int lane = s & 63;
    const int wid  = s >> 6;

    __shared__ float s_wtot[4];        // per-wave cumprod totals
    __shared__ float s_rgb[4][3];      // per-wave rgb partial sums

    // ---- load point ----
    const float* rp = ray_pts + ((size_t)r * N_SAMP + s) * 3;
    const float px = rp[0], py = rp[1], pz = rp[2];

    // ---- grid coords ----
    float ux = fminf(fmaxf((px - kXyzMin) * kScale, 0.0f), 159.0f);
    float uy = fminf(fmaxf((py - kXyzMin) * kScale, 0.0f), 159.0f);
    float uz = fminf(fmaxf((pz - kXyzMin) * kScale, 0.0f), 159.0f);
    int x0 = (int)floorf(ux), y0 = (int)floorf(uy), z0 = (int)floorf(uz);
    int x1 = min(x0 + 1, 159), y1 = min(y0 + 1, 159), z1 = min(z0 + 1, 159);
    float fx = ux - (float)x0, fy = uy - (float)y0, fz = uz - (float)z0;
    float gx = 1.0f - fx, gy = 1.0f - fy, gz = 1.0f - fz;

    // flat offsets (channel 0); all fit in int32 (4 * 4.096e6 < 2^31)
    const int o00 = (x0 * GRID_N + y0) * GRID_N;
    const int o01 = (x0 * GRID_N + y1) * GRID_N;
    const int o10 = (x1 * GRID_N + y0) * GRID_N;
    const int o11 = (x1 * GRID_N + y1) * GRID_N;

    // trilinear weights per corner
    const float w000 = gx * gy * gz, w001 = gx * gy * fz;
    const float w010 = gx * fy * gz, w011 = gx * fy * fz;
    const float w100 = fx * gy * gz, w101 = fx * gy * fz;
    const float w110 = fx * fy * gz, w111 = fx * fy * fz;

    // ---- density sample ----
    float d =
        dgrid[o00 + z0] * w000 + dgrid[o00 + z1] * w001 +
        dgrid[o01 + z0] * w010 + dgrid[o01 + z1] * w011 +
        dgrid[o10 + z0] * w100 + dgrid[o10 + z1] * w101 +
        dgrid[o11 + z0] * w110 + dgrid[o11 + z1] * w111;

    // alpha = 1 - (1 + exp(d + shift))^(-interval)
    const float e   = expf(d + kActShift);
    const float sp  = log1pf(e);                  // softplus; inf-safe
    const float om  = expf(-kInterval * sp);      // (1-alpha)
    const float alpha = 1.0f - om;

    // ---- exclusive cumprod of (1-alpha) across the 256 samples ----
    // wave-level inclusive product scan
    float v = om;
    #pragma unroll
    for (int off = 1; off < 64; off <<= 1) {
        float o = __shfl_up(v, off, 64);
        if (lane >= off) v *= o;
    }
    if (lane == 63) s_wtot[wid] = v;
    __syncthreads();
    float wpref = 1.0f;
    #pragma unroll
    for (int w = 0; w < 4; ++w)
        if (w < wid) wpref *= s_wtot[w];
    const float total = s_wtot[0] * s_wtot[1] * s_wtot[2] * s_wtot[3];

    float excl = __shfl_up(v, 1, 64);
    if (lane == 0) excl = 1.0f;
    const float T  = wpref * excl;     // transmittance before this sample
    const float ws = T * alpha;        // weight

    // coalesced weights write
    out_w[(size_t)r * N_SAMP + s] = ws;

    // ---- color sample (3 channels) + sigmoid ----
    float contrib[3];
    #pragma unroll
    for (int c = 0; c < 3; ++c) {
        const float* g = kgrid + (size_t)c * GRID_VOX;
        float k =
            g[o00 + z0] * w000 + g[o00 + z1] * w001 +
            g[o01 + z0] * w010 + g[o01 + z1] * w011 +
            g[o10 + z0] * w100 + g[o10 + z1] * w101 +
            g[o11 + z0] * w110 + g[o11 + z1] * w111;
        contrib[c] = ws * sigmoidf_(k);
    }

    // ---- block reduction of weighted rgb ----
    #pragma unroll
    for (int c = 0; c < 3; ++c) {
        float x = contrib[c];
        #pragma unroll
        for (int off = 32; off >= 1; off >>= 1)
            x += __shfl_xor(x, off, 64);
        if (lane == 0) s_rgb[wid][c] = x;
    }
    __syncthreads();

    if (s == 0) {
        #pragma unroll
        for (int c = 0; c < 3; ++c) {
            float acc = s_rgb[0][c] + s_rgb[1][c] + s_rgb[2][c] + s_rgb[3][c];
            out_rgb[r * 3 + c] = acc + total;   // + alphainv_last
        }
        out_ainv[r] = total;
    }
}

extern "C" void kernel_launch(void* const* d_in, const int* in_sizes, int n_in,
                              void* d_out, int out_size, void* d_ws, size_t ws_size,
                              hipStream_t stream) {
    const float* ray_pts = (const float*)d_in[0];
    const float* dgrid   = (const float*)d_in[1];
    const float* kgrid   = (const float*)d_in[2];

    float* out_rgb  = (float*)d_out;                       // 16384*3
    float* out_w    = out_rgb + (size_t)N_RAYS * 3;        // 16384*256
    float* out_ainv = out_w + (size_t)N_RAYS * N_SAMP;     // 16384

    render_kernel<<<N_RAYS, N_SAMP, 0, stream>>>(
        ray_pts, dgrid, kgrid, out_rgb, out_w, out_ainv);
}

// Round 2
// 356.075 us; speedup vs baseline: 3.1454x; 3.1454x over previous
//
#include <hip/hip_runtime.h>

// Problem constants (from reference)
#define N_RAYS   16384
#define N_SAMP   256
#define GRID_N   160
#define GRID_VOX (GRID_N * GRID_N * GRID_N)   // 4,096,000

__device__ __constant__ float kXyzMin   = -1.2f;
__device__ __constant__ float kScale    = 159.0f / 2.4f;          // 66.25
__device__ __constant__ float kActShift = -9.21024036697530f;     // log(1/(1-1e-4)-1)
__device__ __constant__ float kInterval = 0.01f;

__device__ __forceinline__ float sigmoidf_(float x) {
    return 1.0f / (1.0f + expf(-x));
}

// ---------------------------------------------------------------------------
// Repack: planar {density[1], k0[3]} -> interleaved float4 per voxel.
// ---------------------------------------------------------------------------
__global__ __launch_bounds__(256)
void repack_kernel(const float* __restrict__ dgrid,
                   const float* __restrict__ kgrid,
                   float4* __restrict__ packed)
{
    int i = blockIdx.x * 256 + threadIdx.x;
    if (i >= GRID_VOX) return;
    float4 v;
    v.x = dgrid[i];
    v.y = kgrid[i];
    v.z = kgrid[i +  GRID_VOX];
    v.w = kgrid[i + 2 * GRID_VOX];
    packed[i] = v;
}

// ---------------------------------------------------------------------------
// Main render over packed AoS grid: 8 corners x 1 float4 gather each.
// ---------------------------------------------------------------------------
__global__ __launch_bounds__(256)
void render_packed_kernel(const float* __restrict__ ray_pts,  // [N_RAYS, N_SAMP, 3]
                          const float4* __restrict__ packed,  // [160^3] (d, r, g, b)
                          float* __restrict__ out_rgb,        // [N_RAYS, 3]
                          float* __restrict__ out_w,          // [N_RAYS, N_SAMP]
                          float* __restrict__ out_ainv)       // [N_RAYS]
{
    const int r    = blockIdx.x;
    const int s    = threadIdx.x;
    const int lane = s & 63;
    const int wid  = s >> 6;

    __shared__ float s_wtot[4];
    __shared__ float s_rgb[4][3];

    const float* rp = ray_pts + ((size_t)r * N_SAMP + s) * 3;
    const float px = rp[0], py = rp[1], pz = rp[2];

    float ux = fminf(fmaxf((px - kXyzMin) * kScale, 0.0f), 159.0f);
    float uy = fminf(fmaxf((py - kXyzMin) * kScale, 0.0f), 159.0f);
    float uz = fminf(fmaxf((pz - kXyzMin) * kScale, 0.0f), 159.0f);
    int x0 = (int)floorf(ux), y0 = (int)floorf(uy), z0 = (int)floorf(uz);
    int x1 = min(x0 + 1, 159), y1 = min(y0 + 1, 159), z1 = min(z0 + 1, 159);
    float fx = ux - (float)x0, fy = uy - (float)y0, fz = uz - (float)z0;
    float gx = 1.0f - fx, gy = 1.0f - fy, gz = 1.0f - fz;

    const int o00 = (x0 * GRID_N + y0) * GRID_N;
    const int o01 = (x0 * GRID_N + y1) * GRID_N;
    const int o10 = (x1 * GRID_N + y0) * GRID_N;
    const int o11 = (x1 * GRID_N + y1) * GRID_N;

    // 8 corner fetches (issue all loads up front; each is one dwordx4)
    const float4 c000 = packed[o00 + z0], c001 = packed[o00 + z1];
    const float4 c010 = packed[o01 + z0], c011 = packed[o01 + z1];
    const float4 c100 = packed[o10 + z0], c101 = packed[o10 + z1];
    const float4 c110 = packed[o11 + z0], c111 = packed[o11 + z1];

    const float w000 = gx * gy * gz, w001 = gx * gy * fz;
    const float w010 = gx * fy * gz, w011 = gx * fy * fz;
    const float w100 = fx * gy * gz, w101 = fx * gy * fz;
    const float w110 = fx * fy * gz, w111 = fx * fy * fz;

    const float d =
        c000.x * w000 + c001.x * w001 + c010.x * w010 + c011.x * w011 +
        c100.x * w100 + c101.x * w101 + c110.x * w110 + c111.x * w111;
    const float kr =
        c000.y * w000 + c001.y * w001 + c010.y * w010 + c011.y * w011 +
        c100.y * w100 + c101.y * w101 + c110.y * w110 + c111.y * w111;
    const float kg =
        c000.z * w000 + c001.z * w001 + c010.z * w010 + c011.z * w011 +
        c100.z * w100 + c101.z * w101 + c110.z * w110 + c111.z * w111;
    const float kb =
        c000.w * w000 + c001.w * w001 + c010.w * w010 + c011.w * w011 +
        c100.w * w100 + c101.w * w101 + c110.w * w110 + c111.w * w111;

    // alpha = 1 - (1 + exp(d + shift))^(-interval)
    const float e     = expf(d + kActShift);
    const float sp    = log1pf(e);               // softplus; inf-safe
    const float om    = expf(-kInterval * sp);   // (1 - alpha)
    const float alpha = 1.0f - om;

    // exclusive cumprod of (1-alpha) across 256 samples
    float v = om;
    #pragma unroll
    for (int off = 1; off < 64; off <<= 1) {
        float o = __shfl_up(v, off, 64);
        if (lane >= off) v *= o;
    }
    if (lane == 63) s_wtot[wid] = v;
    __syncthreads();
    float wpref = 1.0f;
    #pragma unroll
    for (int w = 0; w < 4; ++w)
        if (w < wid) wpref *= s_wtot[w];
    const float total = s_wtot[0] * s_wtot[1] * s_wtot[2] * s_wtot[3];

    float excl = __shfl_up(v, 1, 64);
    if (lane == 0) excl = 1.0f;
    const float T  = wpref * excl;
    const float ws = T * alpha;

    out_w[(size_t)r * N_SAMP + s] = ws;

    float contrib[3];
    contrib[0] = ws * sigmoidf_(kr);
    contrib[1] = ws * sigmoidf_(kg);
    contrib[2] = ws * sigmoidf_(kb);

    #pragma unroll
    for (int c = 0; c < 3; ++c) {
        float x = contrib[c];
        #pragma unroll
        for (int off = 32; off >= 1; off >>= 1)
            x += __shfl_xor(x, off, 64);
        if (lane == 0) s_rgb[wid][c] = x;
    }
    __syncthreads();

    if (s == 0) {
        #pragma unroll
        for (int c = 0; c < 3; ++c) {
            float acc = s_rgb[0][c] + s_rgb[1][c] + s_rgb[2][c] + s_rgb[3][c];
            out_rgb[r * 3 + c] = acc + total;   // + alphainv_last
        }
        out_ainv[r] = total;
    }
}

// ---------------------------------------------------------------------------
// Fallback (round-1 kernel) if workspace is too small for the packed grid.
// ---------------------------------------------------------------------------
__global__ __launch_bounds__(256)
void render_kernel(const float* __restrict__ ray_pts,
                   const float* __restrict__ dgrid,
                   const float* __restrict__ kgrid,
                   float* __restrict__ out_rgb,
                   float* __restrict__ out_w,
                   float* __restrict__ out_ainv)
{
    const int r    = blockIdx.x;
    const int s    = threadIdx.x;
    const int lane = s & 63;
    const int wid  = s >> 6;

    __shared__ float s_wtot[4];
    __shared__ float s_rgb[4][3];

    const float* rp = ray_pts + ((size_t)r * N_SAMP + s) * 3;
    const float px = rp[0], py = rp[1], pz = rp[2];

    float ux = fminf(fmaxf((px - kXyzMin) * kScale, 0.0f), 159.0f);
    float uy = fminf(fmaxf((py - kXyzMin) * kScale, 0.0f), 159.0f);
    float uz = fminf(fmaxf((pz - kXyzMin) * kScale, 0.0f), 159.0f);
    int x0 = (int)floorf(ux), y0 = (int)floorf(uy), z0 = (int)floorf(uz);
    int x1 = min(x0 + 1, 159), y1 = min(y0 + 1, 159), z1 = min(z0 + 1, 159);
    float fx = ux - (float)x0, fy = uy - (float)y0, fz = uz - (float)z0;
    float gx = 1.0f - fx, gy = 1.0f - fy, gz = 1.0f - fz;

    const int o00 = (x0 * GRID_N + y0) * GRID_N;
    const int o01 = (x0 * GRID_N + y1) * GRID_N;
    const int o10 = (x1 * GRID_N + y0) * GRID_N;
    const int o11 = (x1 * GRID_N + y1) * GRID_N;

    const float w000 = gx * gy * gz, w001 = gx * gy * fz;
    const float w010 = gx * fy * gz, w011 = gx * fy * fz;
    const float w100 = fx * gy * gz, w101 = fx * gy * fz;
    const float w110 = fx * fy * gz, w111 = fx * fy * fz;

    float d =
        dgrid[o00 + z0] * w000 + dgrid[o00 + z1] * w001 +
        dgrid[o01 + z0] * w010 + dgrid[o01 + z1] * w011 +
        dgrid[o10 + z0] * w100 + dgrid[o10 + z1] * w101 +
        dgrid[o11 + z0] * w110 + dgrid[o11 + z1] * w111;

    const float e   = expf(d + kActShift);
    const float sp  = log1pf(e);
    const float om  = expf(-kInterval * sp);
    const float alpha = 1.0f - om;

    float v = om;
    #pragma unroll
    for (int off = 1; off < 64; off <<= 1) {
        float o = __shfl_up(v, off, 64);
        if (lane >= off) v *= o;
    }
    if (lane == 63) s_wtot[wid] = v;
    __syncthreads();
    float wpref = 1.0f;
    #pragma unroll
    for (int w = 0; w < 4; ++w)
        if (w < wid) wpref *= s_wtot[w];
    const float total = s_wtot[0] * s_wtot[1] * s_wtot[2] * s_wtot[3];

    float excl = __shfl_up(v, 1, 64);
    if (lane == 0) excl = 1.0f;
    const float T  = wpref * excl;
    const float ws = T * alpha;

    out_w[(size_t)r * N_SAMP + s] = ws;

    float contrib[3];
    #pragma unroll
    for (int c = 0; c < 3; ++c) {
        const float* g = kgrid + (size_t)c * GRID_VOX;
        float k =
            g[o00 + z0] * w000 + g[o00 + z1] * w001 +
            g[o01 + z0] * w010 + g[o01 + z1] * w011 +
            g[o10 + z0] * w100 + g[o10 + z1] * w101 +
            g[o11 + z0] * w110 + g[o11 + z1] * w111;
        contrib[c] = ws * sigmoidf_(k);
    }

    #pragma unroll
    for (int c = 0; c < 3; ++c) {
        float x = contrib[c];
        #pragma unroll
        for (int off = 32; off >= 1; off >>= 1)
            x += __shfl_xor(x, off, 64);
        if (lane == 0) s_rgb[wid][c] = x;
    }
    __syncthreads();

    if (s == 0) {
        #pragma unroll
        for (int c = 0; c < 3; ++c) {
            float acc = s_rgb[0][c] + s_rgb[1][c] + s_rgb[2][c] + s_rgb[3][c];
            out_rgb[r * 3 + c] = acc + total;
        }
        out_ainv[r] = total;
    }
}

extern "C" void kernel_launch(void* const* d_in, const int* in_sizes, int n_in,
                              void* d_out, int out_size, void* d_ws, size_t ws_size,
                              hipStream_t stream) {
    const float* ray_pts = (const float*)d_in[0];
    const float* dgrid   = (const float*)d_in[1];
    const float* kgrid   = (const float*)d_in[2];

    float* out_rgb  = (float*)d_out;                       // 16384*3
    float* out_w    = out_rgb + (size_t)N_RAYS * 3;        // 16384*256
    float* out_ainv = out_w + (size_t)N_RAYS * N_SAMP;     // 16384

    const size_t packed_bytes = (size_t)GRID_VOX * sizeof(float4);  // 65.5 MB

    if (ws_size >= packed_bytes) {
        float4* packed = (float4*)d_ws;
        repack_kernel<<<(GRID_VOX + 255) / 256, 256, 0, stream>>>(dgrid, kgrid, packed);
        render_packed_kernel<<<N_RAYS, N_SAMP, 0, stream>>>(
            ray_pts, packed, out_rgb, out_w, out_ainv);
    } else {
        render_kernel<<<N_RAYS, N_SAMP, 0, stream>>>(
            ray_pts, dgrid, kgrid, out_rgb, out_w, out_ainv);
    }
}

// Round 3
// 191.074 us; speedup vs baseline: 5.8616x; 1.8635x over previous
//
#include <hip/hip_runtime.h>

// Problem constants (from reference)
#define N_RAYS   16384
#define N_SAMP   256
#define GRID_N   160
#define GRID_VOX (GRID_N * GRID_N * GRID_N)   // 4,096,000
#define GB       80                            // 2x2x2 blocks per axis
#define NBLK     (GB * GB * GB)                // 512,000 blocks per copy
#define COPY_VOX (NBLK * 8)                    // 4,096,000 voxels per copy

__device__ __constant__ float kXyzMin   = -1.2f;
__device__ __constant__ float kScale    = 159.0f / 2.4f;          // 66.25
__device__ __constant__ float kActShift = -9.21024036697530f;     // log(1/(1-1e-4)-1)
__device__ __constant__ float kInterval = 0.01f;

__device__ __forceinline__ float sigmoidf_(float x) {
    return 1.0f / (1.0f + expf(-x));
}

// f32 -> bf16 bits, round-nearest-even
__device__ __forceinline__ unsigned int f2bf(float f) {
    unsigned int u = __float_as_uint(f);
    return (u + 0x7fffu + ((u >> 16) & 1u)) >> 16;
}
__device__ __forceinline__ float bf_lo(unsigned int u) {
    return __uint_as_float(u << 16);
}
__device__ __forceinline__ float bf_hi(unsigned int u) {
    return __uint_as_float(u & 0xffff0000u);
}

// ---------------------------------------------------------------------------
// Repack planar f32 {density, k0.rgb} into parity-replicated bf16 2x2x2-block
// grid. Copies = YP*2 (parity py in [0,YP), pz in [0,2)). Voxel = 8B
// (d|r<<16, g|b<<16); block = 8 voxels = 64B = one cacheline.
// Voxel linear index within copy: ((xb*80+yb)*80+zb)*8 + sx*4 + sy*2 + sz,
// where  x = xb*2+sx,  y = py + yb*2 + sy,  z = pz + zb*2 + sz.
// ---------------------------------------------------------------------------
template<int YP>
__global__ __launch_bounds__(256)
void repack_kernel(const float* __restrict__ dgrid,
                   const float* __restrict__ kgrid,
                   uint2* __restrict__ out)
{
    const int i = blockIdx.x * 256 + threadIdx.x;   // grid sized exactly
    const int v  = i & 7;
    const int sx = v >> 2, sy = (v >> 1) & 1, sz = v & 1;
    int b = i >> 3;
    const int zb = b % GB; b /= GB;
    const int yb = b % GB; b /= GB;
    const int xb = b % GB; const int c = b / GB;
    const int py = (YP == 2) ? (c >> 1) : 0;
    const int pz = (YP == 2) ? (c & 1)  : c;

    const int x = xb * 2 + sx;                       // <= 159 always
    const int y = min(py + yb * 2 + sy, GRID_N - 1); // pad row dup-clamped
    const int z = min(pz + zb * 2 + sz, GRID_N - 1);
    const int g = (x * GRID_N + y) * GRID_N + z;

    const unsigned int d  = f2bf(dgrid[g]);
    const unsigned int kr = f2bf(kgrid[g]);
    const unsigned int kg = f2bf(kgrid[g + GRID_VOX]);
    const unsigned int kb = f2bf(kgrid[g + 2 * GRID_VOX]);

    uint2 o;
    o.x = d  | (kr << 16);
    o.y = kg | (kb << 16);
    out[i] = o;
}

// ---------------------------------------------------------------------------
// Render over the replicated block grid.
// YP==2: pick copy (y0&1, z0&1); per x-corner one 32B chunk (2 float4s).
// YP==1: pick copy (z0&1); per (x,y) corner one 16B float4 (z-pair).
// ---------------------------------------------------------------------------
template<int YP>
__global__ __launch_bounds__(256)
void render_blk_kernel(const float* __restrict__ ray_pts,  // [N_RAYS, N_SAMP, 3]
                       const float4* __restrict__ P,       // packed copies
                       float* __restrict__ out_rgb,        // [N_RAYS, 3]
                       float* __restrict__ out_w,          // [N_RAYS, N_SAMP]
                       float* __restrict__ out_ainv)       // [N_RAYS]
{
    const int r    = blockIdx.x;
    const int s    = threadIdx.x;
    const int lane = s & 63;
    const int wid  = s >> 6;

    __shared__ float s_wtot[4];
    __shared__ float s_rgb[4][3];

    const float* rp = ray_pts + ((size_t)r * N_SAMP + s) * 3;
    const float px = rp[0], py_ = rp[1], pz_ = rp[2];

    float ux = fminf(fmaxf((px  - kXyzMin) * kScale, 0.0f), 159.0f);
    float uy = fminf(fmaxf((py_ - kXyzMin) * kScale, 0.0f), 159.0f);
    float uz = fminf(fmaxf((pz_ - kXyzMin) * kScale, 0.0f), 159.0f);
    int x0 = min((int)floorf(ux), GRID_N - 2);   // boundary: fx becomes 1.0
    int y0 = min((int)floorf(uy), GRID_N - 2);
    int z0 = min((int)floorf(uz), GRID_N - 2);
    const float fx = ux - (float)x0, fy = uy - (float)y0, fz = uz - (float)z0;
    const float gx = 1.0f - fx, gy = 1.0f - fy, gz = 1.0f - fz;

    const int zp = z0 & 1, zb = z0 >> 1;
    const int x1 = x0 + 1;

    // q00=(x0,y0,z-pair) q01=(x0,y1,..) q10=(x1,y0,..) q11=(x1,y1,..)
    float4 q00, q01, q10, q11;
    if (YP == 2) {
        const int yp = y0 & 1, yb = y0 >> 1;
        const float4* B = P + (size_t)(yp * 2 + zp) * (NBLK * 4);
        const int a0 = (((x0 >> 1) * GB + yb) * GB + zb) * 4 + (x0 & 1) * 2;
        const int a1 = (((x1 >> 1) * GB + yb) * GB + zb) * 4 + (x1 & 1) * 2;
        q00 = B[a0]; q01 = B[a0 + 1];
        q10 = B[a1]; q11 = B[a1 + 1];
    } else {
        const int y1 = y0 + 1;
        const int yb0 = y0 >> 1, sy0 = y0 & 1;
        const int yb1 = y1 >> 1, sy1 = y1 & 1;
        const float4* B = P + (size_t)zp * (NBLK * 4);
        q00 = B[(((x0 >> 1) * GB + yb0) * GB + zb) * 4 + (x0 & 1) * 2 + sy0];
        q01 = B[(((x0 >> 1) * GB + yb1) * GB + zb) * 4 + (x0 & 1) * 2 + sy1];
        q10 = B[(((x1 >> 1) * GB + yb0) * GB + zb) * 4 + (x1 & 1) * 2 + sy0];
        q11 = B[(((x1 >> 1) * GB + yb1) * GB + zb) * 4 + (x1 & 1) * 2 + sy1];
    }

    float d = 0.f, kr = 0.f, kg = 0.f, kb = 0.f;
    {
        // each float4: (.x,.y) = voxel at z0, (.z,.w) = voxel at z1
        const float wxy00 = gx * gy, wxy01 = gx * fy;
        const float wxy10 = fx * gy, wxy11 = fx * fy;
        #define ACC(Q, WXY)                                               \
        {                                                                 \
            const unsigned a0_ = __float_as_uint((Q).x);                  \
            const unsigned b0_ = __float_as_uint((Q).y);                  \
            const unsigned a1_ = __float_as_uint((Q).z);                  \
            const unsigned b1_ = __float_as_uint((Q).w);                  \
            const float w0_ = (WXY) * gz, w1_ = (WXY) * fz;               \
            d  += w0_ * bf_lo(a0_) + w1_ * bf_lo(a1_);                    \
            kr += w0_ * bf_hi(a0_) + w1_ * bf_hi(a1_);                    \
            kg += w0_ * bf_lo(b0_) + w1_ * bf_lo(b1_);                    \
            kb += w0_ * bf_hi(b0_) + w1_ * bf_hi(b1_);                    \
        }
        ACC(q00, wxy00); ACC(q01, wxy01); ACC(q10, wxy10); ACC(q11, wxy11);
        #undef ACC
    }

    // alpha = 1 - (1 + exp(d + shift))^(-interval)
    const float e     = expf(d + kActShift);
    const float sp    = log1pf(e);               // softplus; inf-safe
    const float om    = expf(-kInterval * sp);   // (1 - alpha)
    const float alpha = 1.0f - om;

    // exclusive cumprod of (1-alpha) across 256 samples
    float v = om;
    #pragma unroll
    for (int off = 1; off < 64; off <<= 1) {
        float o = __shfl_up(v, off, 64);
        if (lane >= off) v *= o;
    }
    if (lane == 63) s_wtot[wid] = v;
    __syncthreads();
    float wpref = 1.0f;
    #pragma unroll
    for (int w = 0; w < 4; ++w)
        if (w < wid) wpref *= s_wtot[w];
    const float total = s_wtot[0] * s_wtot[1] * s_wtot[2] * s_wtot[3];

    float excl = __shfl_up(v, 1, 64);
    if (lane == 0) excl = 1.0f;
    const float T  = wpref * excl;
    const float ws = T * alpha;

    out_w[(size_t)r * N_SAMP + s] = ws;

    float contrib[3];
    contrib[0] = ws * sigmoidf_(kr);
    contrib[1] = ws * sigmoidf_(kg);
    contrib[2] = ws * sigmoidf_(kb);

    #pragma unroll
    for (int c = 0; c < 3; ++c) {
        float x = contrib[c];
        #pragma unroll
        for (int off = 32; off >= 1; off >>= 1)
            x += __shfl_xor(x, off, 64);
        if (lane == 0) s_rgb[wid][c] = x;
    }
    __syncthreads();

    if (s == 0) {
        #pragma unroll
        for (int c = 0; c < 3; ++c) {
            float acc = s_rgb[0][c] + s_rgb[1][c] + s_rgb[2][c] + s_rgb[3][c];
            out_rgb[r * 3 + c] = acc + total;   // + alphainv_last
        }
        out_ainv[r] = total;
    }
}

// ---------------------------------------------------------------------------
// Last-resort fallback (round-1 planar kernel) if ws is tiny.
// ---------------------------------------------------------------------------
__global__ __launch_bounds__(256)
void render_kernel(const float* __restrict__ ray_pts,
                   const float* __restrict__ dgrid,
                   const float* __restrict__ kgrid,
                   float* __restrict__ out_rgb,
                   float* __restrict__ out_w,
                   float* __restrict__ out_ainv)
{
    const int r    = blockIdx.x;
    const int s    = threadIdx.x;
    const int lane = s & 63;
    const int wid  = s >> 6;

    __shared__ float s_wtot[4];
    __shared__ float s_rgb[4][3];

    const float* rp = ray_pts + ((size_t)r * N_SAMP + s) * 3;
    const float px = rp[0], py = rp[1], pz = rp[2];

    float ux = fminf(fmaxf((px - kXyzMin) * kScale, 0.0f), 159.0f);
    float uy = fminf(fmaxf((py - kXyzMin) * kScale, 0.0f), 159.0f);
    float uz = fminf(fmaxf((pz - kXyzMin) * kScale, 0.0f), 159.0f);
    int x0 = (int)floorf(ux), y0 = (int)floorf(uy), z0 = (int)floorf(uz);
    int x1 = min(x0 + 1, 159), y1 = min(y0 + 1, 159), z1 = min(z0 + 1, 159);
    float fx = ux - (float)x0, fy = uy - (float)y0, fz = uz - (float)z0;
    float gx = 1.0f - fx, gy = 1.0f - fy, gz = 1.0f - fz;

    const int o00 = (x0 * GRID_N + y0) * GRID_N;
    const int o01 = (x0 * GRID_N + y1) * GRID_N;
    const int o10 = (x1 * GRID_N + y0) * GRID_N;
    const int o11 = (x1 * GRID_N + y1) * GRID_N;

    const float w000 = gx * gy * gz, w001 = gx * gy * fz;
    const float w010 = gx * fy * gz, w011 = gx * fy * fz;
    const float w100 = fx * gy * gz, w101 = fx * gy * fz;
    const float w110 = fx * fy * gz, w111 = fx * fy * fz;

    float d =
        dgrid[o00 + z0] * w000 + dgrid[o00 + z1] * w001 +
        dgrid[o01 + z0] * w010 + dgrid[o01 + z1] * w011 +
        dgrid[o10 + z0] * w100 + dgrid[o10 + z1] * w101 +
        dgrid[o11 + z0] * w110 + dgrid[o11 + z1] * w111;

    const float e   = expf(d + kActShift);
    const float sp  = log1pf(e);
    const float om  = expf(-kInterval * sp);
    const float alpha = 1.0f - om;

    float v = om;
    #pragma unroll
    for (int off = 1; off < 64; off <<= 1) {
        float o = __shfl_up(v, off, 64);
        if (lane >= off) v *= o;
    }
    if (lane == 63) s_wtot[wid] = v;
    __syncthreads();
    float wpref = 1.0f;
    #pragma unroll
    for (int w = 0; w < 4; ++w)
        if (w < wid) wpref *= s_wtot[w];
    const float total = s_wtot[0] * s_wtot[1] * s_wtot[2] * s_wtot[3];

    float excl = __shfl_up(v, 1, 64);
    if (lane == 0) excl = 1.0f;
    const float T  = wpref * excl;
    const float ws = T * alpha;

    out_w[(size_t)r * N_SAMP + s] = ws;

    float contrib[3];
    #pragma unroll
    for (int c = 0; c < 3; ++c) {
        const float* g = kgrid + (size_t)c * GRID_VOX;
        float k =
            g[o00 + z0] * w000 + g[o00 + z1] * w001 +
            g[o01 + z0] * w010 + g[o01 + z1] * w011 +
            g[o10 + z0] * w100 + g[o10 + z1] * w101 +
            g[o11 + z0] * w110 + g[o11 + z1] * w111;
        contrib[c] = ws * sigmoidf_(k);
    }

    #pragma unroll
    for (int c = 0; c < 3; ++c) {
        float x = contrib[c];
        #pragma unroll
        for (int off = 32; off >= 1; off >>= 1)
            x += __shfl_xor(x, off, 64);
        if (lane == 0) s_rgb[wid][c] = x;
    }
    __syncthreads();

    if (s == 0) {
        #pragma unroll
        for (int c = 0; c < 3; ++c) {
            float acc = s_rgb[0][c] + s_rgb[1][c] + s_rgb[2][c] + s_rgb[3][c];
            out_rgb[r * 3 + c] = acc + total;
        }
        out_ainv[r] = total;
    }
}

extern "C" void kernel_launch(void* const* d_in, const int* in_sizes, int n_in,
                              void* d_out, int out_size, void* d_ws, size_t ws_size,
                              hipStream_t stream) {
    const float* ray_pts = (const float*)d_in[0];
    const float* dgrid   = (const float*)d_in[1];
    const float* kgrid   = (const float*)d_in[2];

    float* out_rgb  = (float*)d_out;                       // 16384*3
    float* out_w    = out_rgb + (size_t)N_RAYS * 3;        // 16384*256
    float* out_ainv = out_w + (size_t)N_RAYS * N_SAMP;     // 16384

    const size_t bytes_per_copy = (size_t)COPY_VOX * 8;    // 32,768,000
    const size_t need4 = 4 * bytes_per_copy;               // 131 MB
    const size_t need2 = 2 * bytes_per_copy;               // 65.5 MB

    if (ws_size >= need4) {
        uint2* packed = (uint2*)d_ws;
        const int total = 4 * COPY_VOX;
        repack_kernel<2><<<total / 256, 256, 0, stream>>>(dgrid, kgrid, packed);
        render_blk_kernel<2><<<N_RAYS, N_SAMP, 0, stream>>>(
            ray_pts, (const float4*)d_ws, out_rgb, out_w, out_ainv);
    } else if (ws_size >= need2) {
        uint2* packed = (uint2*)d_ws;
        const int total = 2 * COPY_VOX;
        repack_kernel<1><<<total / 256, 256, 0, stream>>>(dgrid, kgrid, packed);
        render_blk_kernel<1><<<N_RAYS, N_SAMP, 0, stream>>>(
            ray_pts, (const float4*)d_ws, out_rgb, out_w, out_ainv);
    } else {
        render_kernel<<<N_RAYS, N_SAMP, 0, stream>>>(
            ray_pts, dgrid, kgrid, out_rgb, out_w, out_ainv);
    }
}